// Round 8
// baseline (108.675 us; speedup 1.0000x reference)
//
#include <hip/hip_runtime.h>
#include <stdint.h>

#define BATCH 32
#define NBOX 8192
#define NGT 128
#define M (NBOX + NGT)     // 8320
#define K_OUT 512
#define MAX_FG 128
#define C_CAP 256          // kth boundary-bucket members (~npos/1024, Poisson)
#define S_CAP 256          // selp members (<= 128 + value-ties)
#define U_CAP 1024         // neg union (<= k2 + boundary bucket)

#define GSPLIT 2
#define GPER (NGT / GSPLIT)                       // 64 gts per split
#define IOU_TPB 256
#define IOU_VPT 2
#define IOU_SPAN (IOU_TPB * IOU_VPT)              // 512 items per block
#define IOU_CB ((M + IOU_SPAN - 1) / IOU_SPAN)    // 17 box-chunks

#define TH_HALF 0x3F000000u                       // bits of 0.5f

// Monotone clamped bucket: v1>v2 => bkt(v1)>=bkt(v2); bkt(v1)>bkt(v2) => v1>v2.
__device__ __forceinline__ unsigned int bkt1024(float ns) {
    unsigned int u = (unsigned int)(ns * 16777216.0f) >> 14;
    return u > 1023u ? 1023u : u;
}

// ---------------------------------------------------------------------------
// Kernel 1 v8: gt-split iou, 2 items/thread (ILP-2), sgt+sga staged in LDS.
// Pipe balance: v7 (1 item/thread, 32 waves/CU) was LDS-pipe-bound
// (36.9k LDS cyc/CU > 26.6k VALU cyc/SIMD). Sharing each sgt/sga read
// across 2 items halves LDS demand (19k/CU) and makes VALU binding
// (~23k/SIMD ~ 9.7us model) with 8 independent div chains per SIMD
// (4 waves x ILP-2) at 1088 blocks (~51% occupancy).
// Output: per (split,b,m) best-bits u32 (H) + argmax label u8 (L).
// Merge semantics (verified v7): h0>=h1 ? L0 : L1 == u64-key first-max.
// Exact __f*_rn / __fdiv_rn arithmetic (bit-exact, absmax 0.0 through R7).
// ---------------------------------------------------------------------------
__global__ __launch_bounds__(256, 4) void iou_kernel(
    const float* __restrict__ boxes,      // [B, NBOX, 4]
    const float* __restrict__ gt_boxes,   // [B, NGT, 4]
    unsigned int*  __restrict__ Hh,       // [GSPLIT, B, M] best bits
    unsigned char* __restrict__ Ll)       // [GSPLIT, B, M] argmax label
{
    const int s  = blockIdx.x % GSPLIT;
    const int cb = (blockIdx.x / GSPLIT) % IOU_CB;
    const int b  = blockIdx.x / (GSPLIT * IOU_CB);
    const int t  = threadIdx.x;
    const int g0 = s * GPER;

    __shared__ float4 sgt[GPER];
    __shared__ float  sga[GPER];
    if (t < GPER) {
        float4 g = ((const float4*)gt_boxes)[b * NGT + g0 + t];
        sgt[t] = g;
        sga[t] = __fmul_rn(__fsub_rn(g.z, g.x), __fsub_rn(g.w, g.y));
    }
    __syncthreads();

    const int m0 = cb * IOU_SPAN + t;
    const int m1 = m0 + IOU_TPB;
    if (m0 >= M) return;                  // implies m1 >= M
    const bool v1 = (m1 < M);

    float4 bb0 = (m0 < NBOX) ? ((const float4*)boxes)[b * NBOX + m0]
                             : ((const float4*)gt_boxes)[b * NGT + (m0 - NBOX)];
    float4 bb1 = make_float4(0.f, 0.f, 1.f, 1.f);
    if (v1) bb1 = (m1 < NBOX) ? ((const float4*)boxes)[b * NBOX + m1]
                              : ((const float4*)gt_boxes)[b * NGT + (m1 - NBOX)];
    float ba0 = __fmul_rn(__fsub_rn(bb0.z, bb0.x), __fsub_rn(bb0.w, bb0.y));
    float ba1 = __fmul_rn(__fsub_rn(bb1.z, bb1.x), __fsub_rn(bb1.w, bb1.y));

    float best0 = -1e30f, best1 = -1e30f;
    int bi0 = 0, bi1 = 0;
    #pragma unroll 4
    for (int g = 0; g < GPER; ++g) {
        float4 gg = sgt[g];
        float  ga = sga[g];
        {   // item 0
            float iymin = fmaxf(bb0.x, gg.x);
            float ixmin = fmaxf(bb0.y, gg.y);
            float iymax = fminf(bb0.z, gg.z);
            float ixmax = fminf(bb0.w, gg.w);
            float ia  = __fmul_rn(fmaxf(__fsub_rn(iymax, iymin), 0.0f),
                                  fmaxf(__fsub_rn(ixmax, ixmin), 0.0f));
            float den = __fsub_rn(__fadd_rn(ba0, ga), ia);
            float iou = __fdiv_rn(ia, den);
            if (iou > best0) { best0 = iou; bi0 = g0 + g; }  // first-max
        }
        {   // item 1
            float iymin = fmaxf(bb1.x, gg.x);
            float ixmin = fmaxf(bb1.y, gg.y);
            float iymax = fminf(bb1.z, gg.z);
            float ixmax = fminf(bb1.w, gg.w);
            float ia  = __fmul_rn(fmaxf(__fsub_rn(iymax, iymin), 0.0f),
                                  fmaxf(__fsub_rn(ixmax, ixmin), 0.0f));
            float den = __fsub_rn(__fadd_rn(ba1, ga), ia);
            float iou = __fdiv_rn(ia, den);
            if (iou > best1) { best1 = iou; bi1 = g0 + g; }
        }
    }
    // best >= 0 here (first iteration always beats -1e30; iou >= 0).
    const size_t base = ((size_t)s * BATCH + b) * M;
    Hh[base + m0] = __float_as_uint(best0);
    Ll[base + m0] = (unsigned char)bi0;
    if (v1) {
        Hh[base + m1] = __float_as_uint(best1);
        Ll[base + m1] = (unsigned char)bi1;
    }
}

// Merge the two splits' results for one item -> global first-max label.
__device__ __forceinline__ int merged_label(
    const unsigned int* __restrict__ H0, const unsigned int* __restrict__ H1,
    const unsigned char* __restrict__ L0, const unsigned char* __restrict__ L1,
    int m) {
    unsigned int h0 = H0[m], h1 = H1[m];
    return (h0 >= h1) ? (int)L0[m] : (int)L1[m];   // tie -> split0 = smaller idx
}

// ---------------------------------------------------------------------------
// Kernel 2 v8: byte-identical to verified v7 select.
// ---------------------------------------------------------------------------
__global__ __launch_bounds__(1024) void select_kernel(
    const float* __restrict__ boxes,
    const float* __restrict__ gt_boxes,
    const int*   __restrict__ gt_labels,
    const float* __restrict__ noise,      // [B, M]
    const unsigned int*  __restrict__ Hh, // [GSPLIT, B, M]
    const unsigned char* __restrict__ Ll, // [GSPLIT, B, M]
    float* __restrict__ out)
{
    const int b = blockIdx.x;
    const int tid = threadIdx.x;

    __shared__ float sh_ns_t[128];             // tail items 8192..8319
    __shared__ unsigned int hist[1024];        // neg hist -> suffix counts
    __shared__ unsigned int hist2[1024];       // pos hist -> suffix counts
    __shared__ unsigned int bctr[1024];        // per-bucket placement counters
    __shared__ unsigned char posmask[M / 8];
    __shared__ unsigned char negmask[M / 8];
    __shared__ float4 sgt[NGT];
    __shared__ int slab[NGT];
    __shared__ float C[C_CAP];
    __shared__ __align__(16) unsigned int   skey[S_CAP + 4];
    __shared__ __align__(16) unsigned short sm[S_CAP + 4];
    __shared__ unsigned int   ukey[U_CAP];
    __shared__ unsigned short um[U_CAP];
    __shared__ unsigned int sh_Bp, sh_needp, sh_cc, sh_n1a, sh_B, sh_kth;

    float* out_bt  = out;
    float* out_cls = out + BATCH * K_OUT * 4;
    float* out_roi = out + BATCH * K_OUT * 5;
    float* out_p2l = out + BATCH * K_OUT * 9;

    const unsigned int*  H0 = Hh + (size_t)b * M;
    const unsigned int*  H1 = Hh + ((size_t)BATCH + b) * M;
    const unsigned char* L0 = Ll + (size_t)b * M;
    const unsigned char* L1 = Ll + ((size_t)BATCH + b) * M;

    // ---- init + stage gt ---------------------------------------------------
    hist[tid] = 0;
    hist2[tid] = 0;
    bctr[tid] = 0;
    if (tid == 0) { sh_cc = 0; sh_n1a = 0; sh_B = 0; sh_kth = 0xBF800000u; }
    if (tid < NGT) {
        sgt[tid]  = ((const float4*)gt_boxes)[b * NGT + tid];
        slab[tid] = gt_labels[b * NGT + tid];
    }
    __syncthreads();

    // ---- load pass: H pairs -> masks + two histograms; noise -> regs -------
    float f[8];                                // this thread's chunk (c = tid)
    unsigned int pb = 0, nb = 0;
    {
        const float4* ns4 = (const float4*)(noise + (size_t)b * M);
        {
            const int c = tid;
            const uint4* h0v = (const uint4*)(H0 + c * 8);
            const uint4* h1v = (const uint4*)(H1 + c * 8);
            uint4 A0 = h0v[0], A1 = h0v[1];
            uint4 B0 = h1v[0], B1 = h1v[1];
            float4 n0 = ns4[2 * c], n1v = ns4[2 * c + 1];
            f[0] = n0.x; f[1] = n0.y; f[2] = n0.z; f[3] = n0.w;
            f[4] = n1v.x; f[5] = n1v.y; f[6] = n1v.z; f[7] = n1v.w;
            unsigned int ha[8] = {A0.x, A0.y, A0.z, A0.w, A1.x, A1.y, A1.z, A1.w};
            unsigned int hb[8] = {B0.x, B0.y, B0.z, B0.w, B1.x, B1.y, B1.z, B1.w};
            #pragma unroll
            for (int k = 0; k < 8; ++k) {
                unsigned int ub = ha[k] > hb[k] ? ha[k] : hb[k];
                if (ub > TH_HALF) {                 // best > 0.5f -> pos
                    pb |= (1u << k);
                    atomicAdd(&hist2[bkt1024(f[k])], 1u);
                } else if (ub < TH_HALF) {          // 0 <= best < 0.5f -> neg
                    nb |= (1u << k);
                    atomicAdd(&hist[bkt1024(f[k])], 1u);
                }
            }
            posmask[c] = (unsigned char)pb;
            negmask[c] = (unsigned char)nb;
        }
        if (tid < 16) {                            // tail chunks 1024..1039
            const int c = 1024 + tid;
            const uint4* h0v = (const uint4*)(H0 + c * 8);
            const uint4* h1v = (const uint4*)(H1 + c * 8);
            uint4 A0 = h0v[0], A1 = h0v[1];
            uint4 B0 = h1v[0], B1 = h1v[1];
            float4 n0 = ns4[2 * c], n1v = ns4[2 * c + 1];
            ((float4*)sh_ns_t)[2 * tid] = n0;
            ((float4*)sh_ns_t)[2 * tid + 1] = n1v;
            float ft[8] = {n0.x, n0.y, n0.z, n0.w, n1v.x, n1v.y, n1v.z, n1v.w};
            unsigned int ha[8] = {A0.x, A0.y, A0.z, A0.w, A1.x, A1.y, A1.z, A1.w};
            unsigned int hb[8] = {B0.x, B0.y, B0.z, B0.w, B1.x, B1.y, B1.z, B1.w};
            unsigned int pb2 = 0, nb2 = 0;
            #pragma unroll
            for (int k = 0; k < 8; ++k) {
                unsigned int ub = ha[k] > hb[k] ? ha[k] : hb[k];
                if (ub > TH_HALF) {
                    pb2 |= (1u << k);
                    atomicAdd(&hist2[bkt1024(ft[k])], 1u);
                } else if (ub < TH_HALF) {
                    nb2 |= (1u << k);
                    atomicAdd(&hist[bkt1024(ft[k])], 1u);
                }
            }
            posmask[c] = (unsigned char)pb2;
            negmask[c] = (unsigned char)nb2;
        }
    }
    __syncthreads();

    // ---- suffix scans: wave 0 -> hist (neg), wave 1 -> hist2 (pos) ---------
    {
        const int wv = tid >> 6, ln = tid & 63;
        if (wv < 2) {
            unsigned int* H = wv ? hist2 : hist;
            unsigned int s[16];
            #pragma unroll
            for (int k = 0; k < 16; ++k) {
                unsigned int v = H[k * 64 + ln];
                #pragma unroll
                for (int off = 1; off < 64; off <<= 1) {
                    unsigned int o = __shfl_down(v, off, 64);
                    if (ln + off < 64) v += o;
                }
                s[k] = v;
            }
            unsigned int after = 0;
            #pragma unroll
            for (int k = 15; k >= 0; --k) {
                unsigned int tot = __shfl(s[k], 0, 64);
                H[k * 64 + ln] = s[k] + after;
                after += tot;
            }
        }
    }
    __syncthreads();
    const unsigned int nneg = hist[0];
    const unsigned int npos = hist2[0];

    // ---- kth = 128th-largest pos noise (capacity-free, exact) --------------
    if (npos >= MAX_FG) {                       // block-uniform branch
        {
            unsigned int S  = hist2[tid];
            unsigned int Sn = (tid < 1023) ? hist2[tid + 1] : 0;
            if (S >= MAX_FG && Sn < MAX_FG) { sh_Bp = tid; sh_needp = MAX_FG - Sn; }
        }
        __syncthreads();
        const unsigned int Bp = sh_Bp, needp = sh_needp;
        #pragma unroll
        for (int k = 0; k < 8; ++k) {
            if (((pb >> k) & 1u) && bkt1024(f[k]) == Bp) {
                unsigned int slot = atomicAdd(&sh_cc, 1u);
                if (slot < C_CAP) C[slot] = f[k];
            }
        }
        if (tid < 16) {
            unsigned int pb2 = posmask[1024 + tid];
            #pragma unroll
            for (int k = 0; k < 8; ++k) {
                if ((pb2 >> k) & 1u) {
                    float v = sh_ns_t[tid * 8 + k];
                    if (bkt1024(v) == Bp) {
                        unsigned int slot = atomicAdd(&sh_cc, 1u);
                        if (slot < C_CAP) C[slot] = v;
                    }
                }
            }
        }
        __syncthreads();
        {   // exact in-bucket value rank: v with #greater < needp <= #greater+#eq
            unsigned int cc = min(sh_cc, (unsigned int)C_CAP);
            if (tid < (int)cc) {
                float my = C[tid];
                unsigned int g = 0, e = 0;
                for (unsigned int j = 0; j < cc; ++j) {
                    float v = C[j];
                    g += (v > my) ? 1u : 0u;
                    e += (v == my) ? 1u : 0u;
                }
                if (g < needp && g + e >= needp) sh_kth = __float_as_uint(my);
            }
        }
        __syncthreads();
    }
    const float kthf = __uint_as_float(sh_kth);

    // ---- selp collection: pos && ns >= kth; store key = bits(2+ns) ---------
    #pragma unroll
    for (int k = 0; k < 8; ++k) {
        if (((pb >> k) & 1u) && f[k] >= kthf) {
            unsigned int slot = atomicAdd(&sh_n1a, 1u);
            if (slot < S_CAP) {
                skey[slot] = __float_as_uint(__fadd_rn(2.0f, f[k]));
                sm[slot]   = (unsigned short)(tid * 8 + k);
            }
        }
    }
    if (tid < 16) {
        unsigned int pb2 = posmask[1024 + tid];
        #pragma unroll
        for (int k = 0; k < 8; ++k) {
            if ((pb2 >> k) & 1u) {
                float v = sh_ns_t[tid * 8 + k];
                if (v >= kthf) {
                    unsigned int slot = atomicAdd(&sh_n1a, 1u);
                    if (slot < S_CAP) {
                        skey[slot] = __float_as_uint(__fadd_rn(2.0f, v));
                        sm[slot]   = (unsigned short)((1024 + tid) * 8 + k);
                    }
                }
            }
        }
    }
    __syncthreads();
    const unsigned int n1 = min(sh_n1a, (unsigned int)S_CAP);
    const unsigned int k2 = K_OUT - n1;         // >= 382 expected
    const bool enough_neg = (nneg >= k2);

    if (tid < 4) { skey[n1 + tid] = 0u; sm[n1 + tid] = 0xFFFFu; }  // pad
    if (enough_neg) {
        unsigned int S  = hist[tid];
        unsigned int Sn = (tid < 1023) ? hist[tid + 1] : 0;
        if (S >= k2 && Sn < k2) sh_B = tid;     // unique writer
    }   // else sh_B stays 0 -> place all negs
    __syncthreads();
    const unsigned int B1 = sh_B;

    // ---- selp exact pairwise rank (vectorized LDS reads) + fg writes -------
    if (tid < (int)n1) {
        unsigned int   ki = skey[tid];
        unsigned short mi = sm[tid];
        unsigned int r = 0;
        for (unsigned int j = 0; j < n1; j += 4) {
            uint4   kv = *(const uint4*)&skey[j];
            ushort4 mv = *(const ushort4*)&sm[j];
            r += (kv.x > ki || (kv.x == ki && mv.x < mi)) ? 1u : 0u;
            r += (kv.y > ki || (kv.y == ki && mv.y < mi)) ? 1u : 0u;
            r += (kv.z > ki || (kv.z == ki && mv.z < mi)) ? 1u : 0u;
            r += (kv.w > ki || (kv.w == ki && mv.w < mi)) ? 1u : 0u;
        }
        int mi_ = mi;
        int lbl = merged_label(H0, H1, L0, L1, mi_);
        float4 roi = (mi_ < NBOX) ? ((const float4*)boxes)[b * NBOX + mi_]
                                  : sgt[mi_ - NBOX];
        ((float4*)out_bt)[b * K_OUT + r] = sgt[lbl];
        out_cls[b * K_OUT + r] = (float)slab[lbl];
        ((float4*)out_roi)[b * K_OUT + r] = roi;
        out_p2l[b * K_OUT + r] = (float)lbl;
    }

    // ---- neg bucket placement: positional, rank-exact ----------------------
    #pragma unroll
    for (int k = 0; k < 8; ++k) {
        if ((nb >> k) & 1u) {
            float v = f[k];
            unsigned int be = bkt1024(v);
            if (be >= B1) {
                unsigned int base = (be < 1023) ? hist[be + 1] : 0;
                unsigned int a = base + atomicAdd(&bctr[be], 1u);
                if (a < U_CAP) {
                    ukey[a] = __float_as_uint(v);   // v >= 0: uint-monotone
                    um[a]   = (unsigned short)(tid * 8 + k);
                }
            }
        }
    }
    if (tid < 16) {
        unsigned int nb2 = negmask[1024 + tid];
        #pragma unroll
        for (int k = 0; k < 8; ++k) {
            if ((nb2 >> k) & 1u) {
                float v = sh_ns_t[tid * 8 + k];
                unsigned int be = bkt1024(v);
                if (be >= B1) {
                    unsigned int base = (be < 1023) ? hist[be + 1] : 0;
                    unsigned int a = base + atomicAdd(&bctr[be], 1u);
                    if (a < U_CAP) {
                        ukey[a] = __float_as_uint(v);
                        um[a]   = (unsigned short)((1024 + tid) * 8 + k);
                    }
                }
            }
        }
    }
    __syncthreads();

    // ---- neg finalize: within-bucket exact rank over own segment -----------
    const unsigned int q = min(hist[B1], (unsigned int)U_CAP);
    for (unsigned int a = tid; a < q; a += 1024) {
        unsigned int   ki = ukey[a];
        unsigned short mi = um[a];
        unsigned int be = bkt1024(__uint_as_float(ki));
        unsigned int base = (be < 1023) ? hist[be + 1] : 0;
        unsigned int end  = min(hist[be], q);
        unsigned int r = base;
        for (unsigned int j = base; j < end; ++j) {
            unsigned int kj = ukey[j];
            if (kj > ki || (kj == ki && um[j] < mi)) ++r;
        }
        if (r < k2) {
            float4 roi = (mi < NBOX) ? ((const float4*)boxes)[b * NBOX + mi]
                                     : sgt[mi - NBOX];
            unsigned int gr = n1 + r;
            ((float4*)out_bt)[b * K_OUT + gr] = make_float4(0.f, 0.f, 0.f, 0.f);
            out_cls[b * K_OUT + gr] = 0.0f;
            ((float4*)out_roi)[b * K_OUT + gr] = roi;
            out_p2l[b * K_OUT + gr] = 0.0f;
        }
    }

    // ---- fallback (statistically impossible: nneg < k2): rest by m asc -----
    if (!enough_neg) {
        __syncthreads();
        const unsigned int k3 = k2 - nneg;
        const float* nsb = noise + (size_t)b * M;
        for (int m = tid; m < M; m += 1024) {
            if (((posmask[m >> 3] >> (m & 7)) & 1) && nsb[m] < kthf) {
                unsigned int r = 0;
                for (int m2 = 0; m2 < m; ++m2)
                    if (((posmask[m2 >> 3] >> (m2 & 7)) & 1) && nsb[m2] < kthf) ++r;
                if (r < k3) {
                    int lbl = merged_label(H0, H1, L0, L1, m);
                    float4 roi = (m < NBOX) ? ((const float4*)boxes)[b * NBOX + m]
                                            : sgt[m - NBOX];
                    unsigned int gr = n1 + nneg + r;
                    ((float4*)out_bt)[b * K_OUT + gr] = sgt[lbl];
                    out_cls[b * K_OUT + gr] = (float)slab[lbl];
                    ((float4*)out_roi)[b * K_OUT + gr] = roi;
                    out_p2l[b * K_OUT + gr] = (float)lbl;
                }
            }
        }
    }
}

extern "C" void kernel_launch(void* const* d_in, const int* in_sizes, int n_in,
                              void* d_out, int out_size, void* d_ws, size_t ws_size,
                              hipStream_t stream) {
    const float* boxes     = (const float*)d_in[0];
    const float* gt_boxes  = (const float*)d_in[1];
    const int*   gt_labels = (const int*)d_in[2];
    const float* noise     = (const float*)d_in[3];
    float* out = (float*)d_out;

    // workspace layout (16B-aligned):
    unsigned int*  Hh = (unsigned int*)d_ws;                      // 2,129,920 B
    unsigned char* Ll = (unsigned char*)d_ws + 2129920;           //   532,480 B

    iou_kernel<<<BATCH * IOU_CB * GSPLIT, IOU_TPB, 0, stream>>>(
        boxes, gt_boxes, Hh, Ll);
    select_kernel<<<BATCH, 1024, 0, stream>>>(
        boxes, gt_boxes, gt_labels, noise, Hh, Ll, out);
}

// Round 9
// 104.711 us; speedup vs baseline: 1.0379x; 1.0379x over previous
//
#include <hip/hip_runtime.h>
#include <stdint.h>

#define BATCH 32
#define NBOX 8192
#define NGT 128
#define M (NBOX + NGT)     // 8320
#define K_OUT 512
#define MAX_FG 128
#define C_CAP 256          // kth boundary-bucket members (~npos/1024, Poisson)
#define S_CAP 256          // selp members (<= 128 + value-ties)
#define U_CAP 1024         // neg union (<= k2 + boundary bucket)

#define GSPLIT 2
#define GPER (NGT / GSPLIT)                       // 64 gts per split
#define IOU_TPB 256
#define IOU_CB ((M + IOU_TPB - 1) / IOU_TPB)      // 33 box-chunks

#define TH_HALF 0x3F000000u                       // bits of 0.5f

// Monotone clamped bucket: v1>v2 => bkt(v1)>=bkt(v2); bkt(v1)>bkt(v2) => v1>v2.
__device__ __forceinline__ unsigned int bkt1024(float ns) {
    unsigned int u = (unsigned int)(ns * 16777216.0f) >> 14;
    return u > 1023u ? 1023u : u;
}

// ---------------------------------------------------------------------------
// Kernel 1 v9: verified v7 structure (gt-split, 1 item/thread, 2112 blocks =
// 33 waves/CU max TLP; sgt+sga LDS-staged). Evidence across v3/v4/v5/v8:
// latency-bound, responds only to wave count (ILP-2 at 17 waves/CU lost 3us;
// ILP-2 at 8.5 waves lost 2; occupancy 12->33 waves won 8.7). Change vs v7:
// unroll 4 -> 8 (more in-flight ds_reads per wave; no occupancy impact at
// ~32 VGPR). Output: best-bits u32 (H) + argmax label u8 (L) per item-split.
// Merge semantics (v7-verified): h0>=h1 ? L0 : L1 == u64-key first-max.
// Exact __f*_rn / __fdiv_rn arithmetic (bit-exact, absmax 0.0 through R8).
// ---------------------------------------------------------------------------
__global__ __launch_bounds__(256, 8) void iou_kernel(
    const float* __restrict__ boxes,      // [B, NBOX, 4]
    const float* __restrict__ gt_boxes,   // [B, NGT, 4]
    unsigned int*  __restrict__ Hh,       // [GSPLIT, B, M] best bits
    unsigned char* __restrict__ Ll)       // [GSPLIT, B, M] argmax label
{
    const int s  = blockIdx.x % GSPLIT;
    const int cb = (blockIdx.x / GSPLIT) % IOU_CB;
    const int b  = blockIdx.x / (GSPLIT * IOU_CB);
    const int t  = threadIdx.x;
    const int g0 = s * GPER;

    __shared__ float4 sgt[GPER];
    __shared__ float  sga[GPER];
    if (t < GPER) {
        float4 g = ((const float4*)gt_boxes)[b * NGT + g0 + t];
        sgt[t] = g;
        sga[t] = __fmul_rn(__fsub_rn(g.z, g.x), __fsub_rn(g.w, g.y));
    }
    __syncthreads();

    const int m = cb * IOU_TPB + t;
    if (m >= M) return;

    float4 bb = (m < NBOX) ? ((const float4*)boxes)[b * NBOX + m]
                           : ((const float4*)gt_boxes)[b * NGT + (m - NBOX)];
    float ba = __fmul_rn(__fsub_rn(bb.z, bb.x), __fsub_rn(bb.w, bb.y));

    float best = -1e30f;
    int bi = 0;
    #pragma unroll 8
    for (int g = 0; g < GPER; ++g) {
        float4 gg = sgt[g];
        float iymin = fmaxf(bb.x, gg.x);
        float ixmin = fmaxf(bb.y, gg.y);
        float iymax = fminf(bb.z, gg.z);
        float ixmax = fminf(bb.w, gg.w);
        float ia  = __fmul_rn(fmaxf(__fsub_rn(iymax, iymin), 0.0f),
                              fmaxf(__fsub_rn(ixmax, ixmin), 0.0f));
        float den = __fsub_rn(__fadd_rn(ba, sga[g]), ia);
        float iou = __fdiv_rn(ia, den);
        if (iou > best) { best = iou; bi = g0 + g; }     // first-max = argmax
    }
    // best >= 0 here (first iteration always beats -1e30; iou >= 0).
    const size_t o = ((size_t)s * BATCH + b) * M + m;
    Hh[o] = __float_as_uint(best);
    Ll[o] = (unsigned char)bi;
}

// Merge the two splits' results for one item -> global first-max label.
__device__ __forceinline__ int merged_label(
    const unsigned int* __restrict__ H0, const unsigned int* __restrict__ H1,
    const unsigned char* __restrict__ L0, const unsigned char* __restrict__ L1,
    int m) {
    unsigned int h0 = H0[m], h1 = H1[m];
    return (h0 >= h1) ? (int)L0[m] : (int)L1[m];   // tie -> split0 = smaller idx
}

// ---------------------------------------------------------------------------
// Kernel 2 v9: byte-identical to verified v7 select.
// ---------------------------------------------------------------------------
__global__ __launch_bounds__(1024) void select_kernel(
    const float* __restrict__ boxes,
    const float* __restrict__ gt_boxes,
    const int*   __restrict__ gt_labels,
    const float* __restrict__ noise,      // [B, M]
    const unsigned int*  __restrict__ Hh, // [GSPLIT, B, M]
    const unsigned char* __restrict__ Ll, // [GSPLIT, B, M]
    float* __restrict__ out)
{
    const int b = blockIdx.x;
    const int tid = threadIdx.x;

    __shared__ float sh_ns_t[128];             // tail items 8192..8319
    __shared__ unsigned int hist[1024];        // neg hist -> suffix counts
    __shared__ unsigned int hist2[1024];       // pos hist -> suffix counts
    __shared__ unsigned int bctr[1024];        // per-bucket placement counters
    __shared__ unsigned char posmask[M / 8];
    __shared__ unsigned char negmask[M / 8];
    __shared__ float4 sgt[NGT];
    __shared__ int slab[NGT];
    __shared__ float C[C_CAP];
    __shared__ __align__(16) unsigned int   skey[S_CAP + 4];
    __shared__ __align__(16) unsigned short sm[S_CAP + 4];
    __shared__ unsigned int   ukey[U_CAP];
    __shared__ unsigned short um[U_CAP];
    __shared__ unsigned int sh_Bp, sh_needp, sh_cc, sh_n1a, sh_B, sh_kth;

    float* out_bt  = out;
    float* out_cls = out + BATCH * K_OUT * 4;
    float* out_roi = out + BATCH * K_OUT * 5;
    float* out_p2l = out + BATCH * K_OUT * 9;

    const unsigned int*  H0 = Hh + (size_t)b * M;
    const unsigned int*  H1 = Hh + ((size_t)BATCH + b) * M;
    const unsigned char* L0 = Ll + (size_t)b * M;
    const unsigned char* L1 = Ll + ((size_t)BATCH + b) * M;

    // ---- init + stage gt ---------------------------------------------------
    hist[tid] = 0;
    hist2[tid] = 0;
    bctr[tid] = 0;
    if (tid == 0) { sh_cc = 0; sh_n1a = 0; sh_B = 0; sh_kth = 0xBF800000u; }
    if (tid < NGT) {
        sgt[tid]  = ((const float4*)gt_boxes)[b * NGT + tid];
        slab[tid] = gt_labels[b * NGT + tid];
    }
    __syncthreads();

    // ---- load pass: H pairs -> masks + two histograms; noise -> regs -------
    float f[8];                                // this thread's chunk (c = tid)
    unsigned int pb = 0, nb = 0;
    {
        const float4* ns4 = (const float4*)(noise + (size_t)b * M);
        {
            const int c = tid;
            const uint4* h0v = (const uint4*)(H0 + c * 8);
            const uint4* h1v = (const uint4*)(H1 + c * 8);
            uint4 A0 = h0v[0], A1 = h0v[1];
            uint4 B0 = h1v[0], B1 = h1v[1];
            float4 n0 = ns4[2 * c], n1v = ns4[2 * c + 1];
            f[0] = n0.x; f[1] = n0.y; f[2] = n0.z; f[3] = n0.w;
            f[4] = n1v.x; f[5] = n1v.y; f[6] = n1v.z; f[7] = n1v.w;
            unsigned int ha[8] = {A0.x, A0.y, A0.z, A0.w, A1.x, A1.y, A1.z, A1.w};
            unsigned int hb[8] = {B0.x, B0.y, B0.z, B0.w, B1.x, B1.y, B1.z, B1.w};
            #pragma unroll
            for (int k = 0; k < 8; ++k) {
                unsigned int ub = ha[k] > hb[k] ? ha[k] : hb[k];
                if (ub > TH_HALF) {                 // best > 0.5f -> pos
                    pb |= (1u << k);
                    atomicAdd(&hist2[bkt1024(f[k])], 1u);
                } else if (ub < TH_HALF) {          // 0 <= best < 0.5f -> neg
                    nb |= (1u << k);
                    atomicAdd(&hist[bkt1024(f[k])], 1u);
                }
            }
            posmask[c] = (unsigned char)pb;
            negmask[c] = (unsigned char)nb;
        }
        if (tid < 16) {                            // tail chunks 1024..1039
            const int c = 1024 + tid;
            const uint4* h0v = (const uint4*)(H0 + c * 8);
            const uint4* h1v = (const uint4*)(H1 + c * 8);
            uint4 A0 = h0v[0], A1 = h0v[1];
            uint4 B0 = h1v[0], B1 = h1v[1];
            float4 n0 = ns4[2 * c], n1v = ns4[2 * c + 1];
            ((float4*)sh_ns_t)[2 * tid] = n0;
            ((float4*)sh_ns_t)[2 * tid + 1] = n1v;
            float ft[8] = {n0.x, n0.y, n0.z, n0.w, n1v.x, n1v.y, n1v.z, n1v.w};
            unsigned int ha[8] = {A0.x, A0.y, A0.z, A0.w, A1.x, A1.y, A1.z, A1.w};
            unsigned int hb[8] = {B0.x, B0.y, B0.z, B0.w, B1.x, B1.y, B1.z, B1.w};
            unsigned int pb2 = 0, nb2 = 0;
            #pragma unroll
            for (int k = 0; k < 8; ++k) {
                unsigned int ub = ha[k] > hb[k] ? ha[k] : hb[k];
                if (ub > TH_HALF) {
                    pb2 |= (1u << k);
                    atomicAdd(&hist2[bkt1024(ft[k])], 1u);
                } else if (ub < TH_HALF) {
                    nb2 |= (1u << k);
                    atomicAdd(&hist[bkt1024(ft[k])], 1u);
                }
            }
            posmask[c] = (unsigned char)pb2;
            negmask[c] = (unsigned char)nb2;
        }
    }
    __syncthreads();

    // ---- suffix scans: wave 0 -> hist (neg), wave 1 -> hist2 (pos) ---------
    {
        const int wv = tid >> 6, ln = tid & 63;
        if (wv < 2) {
            unsigned int* H = wv ? hist2 : hist;
            unsigned int s[16];
            #pragma unroll
            for (int k = 0; k < 16; ++k) {
                unsigned int v = H[k * 64 + ln];
                #pragma unroll
                for (int off = 1; off < 64; off <<= 1) {
                    unsigned int o = __shfl_down(v, off, 64);
                    if (ln + off < 64) v += o;
                }
                s[k] = v;
            }
            unsigned int after = 0;
            #pragma unroll
            for (int k = 15; k >= 0; --k) {
                unsigned int tot = __shfl(s[k], 0, 64);
                H[k * 64 + ln] = s[k] + after;
                after += tot;
            }
        }
    }
    __syncthreads();
    const unsigned int nneg = hist[0];
    const unsigned int npos = hist2[0];

    // ---- kth = 128th-largest pos noise (capacity-free, exact) --------------
    if (npos >= MAX_FG) {                       // block-uniform branch
        {
            unsigned int S  = hist2[tid];
            unsigned int Sn = (tid < 1023) ? hist2[tid + 1] : 0;
            if (S >= MAX_FG && Sn < MAX_FG) { sh_Bp = tid; sh_needp = MAX_FG - Sn; }
        }
        __syncthreads();
        const unsigned int Bp = sh_Bp, needp = sh_needp;
        #pragma unroll
        for (int k = 0; k < 8; ++k) {
            if (((pb >> k) & 1u) && bkt1024(f[k]) == Bp) {
                unsigned int slot = atomicAdd(&sh_cc, 1u);
                if (slot < C_CAP) C[slot] = f[k];
            }
        }
        if (tid < 16) {
            unsigned int pb2 = posmask[1024 + tid];
            #pragma unroll
            for (int k = 0; k < 8; ++k) {
                if ((pb2 >> k) & 1u) {
                    float v = sh_ns_t[tid * 8 + k];
                    if (bkt1024(v) == Bp) {
                        unsigned int slot = atomicAdd(&sh_cc, 1u);
                        if (slot < C_CAP) C[slot] = v;
                    }
                }
            }
        }
        __syncthreads();
        {   // exact in-bucket value rank: v with #greater < needp <= #greater+#eq
            unsigned int cc = min(sh_cc, (unsigned int)C_CAP);
            if (tid < (int)cc) {
                float my = C[tid];
                unsigned int g = 0, e = 0;
                for (unsigned int j = 0; j < cc; ++j) {
                    float v = C[j];
                    g += (v > my) ? 1u : 0u;
                    e += (v == my) ? 1u : 0u;
                }
                if (g < needp && g + e >= needp) sh_kth = __float_as_uint(my);
            }
        }
        __syncthreads();
    }
    const float kthf = __uint_as_float(sh_kth);

    // ---- selp collection: pos && ns >= kth; store key = bits(2+ns) ---------
    #pragma unroll
    for (int k = 0; k < 8; ++k) {
        if (((pb >> k) & 1u) && f[k] >= kthf) {
            unsigned int slot = atomicAdd(&sh_n1a, 1u);
            if (slot < S_CAP) {
                skey[slot] = __float_as_uint(__fadd_rn(2.0f, f[k]));
                sm[slot]   = (unsigned short)(tid * 8 + k);
            }
        }
    }
    if (tid < 16) {
        unsigned int pb2 = posmask[1024 + tid];
        #pragma unroll
        for (int k = 0; k < 8; ++k) {
            if ((pb2 >> k) & 1u) {
                float v = sh_ns_t[tid * 8 + k];
                if (v >= kthf) {
                    unsigned int slot = atomicAdd(&sh_n1a, 1u);
                    if (slot < S_CAP) {
                        skey[slot] = __float_as_uint(__fadd_rn(2.0f, v));
                        sm[slot]   = (unsigned short)((1024 + tid) * 8 + k);
                    }
                }
            }
        }
    }
    __syncthreads();
    const unsigned int n1 = min(sh_n1a, (unsigned int)S_CAP);
    const unsigned int k2 = K_OUT - n1;         // >= 382 expected
    const bool enough_neg = (nneg >= k2);

    if (tid < 4) { skey[n1 + tid] = 0u; sm[n1 + tid] = 0xFFFFu; }  // pad
    if (enough_neg) {
        unsigned int S  = hist[tid];
        unsigned int Sn = (tid < 1023) ? hist[tid + 1] : 0;
        if (S >= k2 && Sn < k2) sh_B = tid;     // unique writer
    }   // else sh_B stays 0 -> place all negs
    __syncthreads();
    const unsigned int B1 = sh_B;

    // ---- selp exact pairwise rank (vectorized LDS reads) + fg writes -------
    if (tid < (int)n1) {
        unsigned int   ki = skey[tid];
        unsigned short mi = sm[tid];
        unsigned int r = 0;
        for (unsigned int j = 0; j < n1; j += 4) {
            uint4   kv = *(const uint4*)&skey[j];
            ushort4 mv = *(const ushort4*)&sm[j];
            r += (kv.x > ki || (kv.x == ki && mv.x < mi)) ? 1u : 0u;
            r += (kv.y > ki || (kv.y == ki && mv.y < mi)) ? 1u : 0u;
            r += (kv.z > ki || (kv.z == ki && mv.z < mi)) ? 1u : 0u;
            r += (kv.w > ki || (kv.w == ki && mv.w < mi)) ? 1u : 0u;
        }
        int mi_ = mi;
        int lbl = merged_label(H0, H1, L0, L1, mi_);
        float4 roi = (mi_ < NBOX) ? ((const float4*)boxes)[b * NBOX + mi_]
                                  : sgt[mi_ - NBOX];
        ((float4*)out_bt)[b * K_OUT + r] = sgt[lbl];
        out_cls[b * K_OUT + r] = (float)slab[lbl];
        ((float4*)out_roi)[b * K_OUT + r] = roi;
        out_p2l[b * K_OUT + r] = (float)lbl;
    }

    // ---- neg bucket placement: positional, rank-exact ----------------------
    #pragma unroll
    for (int k = 0; k < 8; ++k) {
        if ((nb >> k) & 1u) {
            float v = f[k];
            unsigned int be = bkt1024(v);
            if (be >= B1) {
                unsigned int base = (be < 1023) ? hist[be + 1] : 0;
                unsigned int a = base + atomicAdd(&bctr[be], 1u);
                if (a < U_CAP) {
                    ukey[a] = __float_as_uint(v);   // v >= 0: uint-monotone
                    um[a]   = (unsigned short)(tid * 8 + k);
                }
            }
        }
    }
    if (tid < 16) {
        unsigned int nb2 = negmask[1024 + tid];
        #pragma unroll
        for (int k = 0; k < 8; ++k) {
            if ((nb2 >> k) & 1u) {
                float v = sh_ns_t[tid * 8 + k];
                unsigned int be = bkt1024(v);
                if (be >= B1) {
                    unsigned int base = (be < 1023) ? hist[be + 1] : 0;
                    unsigned int a = base + atomicAdd(&bctr[be], 1u);
                    if (a < U_CAP) {
                        ukey[a] = __float_as_uint(v);
                        um[a]   = (unsigned short)((1024 + tid) * 8 + k);
                    }
                }
            }
        }
    }
    __syncthreads();

    // ---- neg finalize: within-bucket exact rank over own segment -----------
    const unsigned int q = min(hist[B1], (unsigned int)U_CAP);
    for (unsigned int a = tid; a < q; a += 1024) {
        unsigned int   ki = ukey[a];
        unsigned short mi = um[a];
        unsigned int be = bkt1024(__uint_as_float(ki));
        unsigned int base = (be < 1023) ? hist[be + 1] : 0;
        unsigned int end  = min(hist[be], q);
        unsigned int r = base;
        for (unsigned int j = base; j < end; ++j) {
            unsigned int kj = ukey[j];
            if (kj > ki || (kj == ki && um[j] < mi)) ++r;
        }
        if (r < k2) {
            float4 roi = (mi < NBOX) ? ((const float4*)boxes)[b * NBOX + mi]
                                     : sgt[mi - NBOX];
            unsigned int gr = n1 + r;
            ((float4*)out_bt)[b * K_OUT + gr] = make_float4(0.f, 0.f, 0.f, 0.f);
            out_cls[b * K_OUT + gr] = 0.0f;
            ((float4*)out_roi)[b * K_OUT + gr] = roi;
            out_p2l[b * K_OUT + gr] = 0.0f;
        }
    }

    // ---- fallback (statistically impossible: nneg < k2): rest by m asc -----
    if (!enough_neg) {
        __syncthreads();
        const unsigned int k3 = k2 - nneg;
        const float* nsb = noise + (size_t)b * M;
        for (int m = tid; m < M; m += 1024) {
            if (((posmask[m >> 3] >> (m & 7)) & 1) && nsb[m] < kthf) {
                unsigned int r = 0;
                for (int m2 = 0; m2 < m; ++m2)
                    if (((posmask[m2 >> 3] >> (m2 & 7)) & 1) && nsb[m2] < kthf) ++r;
                if (r < k3) {
                    int lbl = merged_label(H0, H1, L0, L1, m);
                    float4 roi = (m < NBOX) ? ((const float4*)boxes)[b * NBOX + m]
                                            : sgt[m - NBOX];
                    unsigned int gr = n1 + nneg + r;
                    ((float4*)out_bt)[b * K_OUT + gr] = sgt[lbl];
                    out_cls[b * K_OUT + gr] = (float)slab[lbl];
                    ((float4*)out_roi)[b * K_OUT + gr] = roi;
                    out_p2l[b * K_OUT + gr] = (float)lbl;
                }
            }
        }
    }
}

extern "C" void kernel_launch(void* const* d_in, const int* in_sizes, int n_in,
                              void* d_out, int out_size, void* d_ws, size_t ws_size,
                              hipStream_t stream) {
    const float* boxes     = (const float*)d_in[0];
    const float* gt_boxes  = (const float*)d_in[1];
    const int*   gt_labels = (const int*)d_in[2];
    const float* noise     = (const float*)d_in[3];
    float* out = (float*)d_out;

    // workspace layout (16B-aligned):
    unsigned int*  Hh = (unsigned int*)d_ws;                      // 2,129,920 B
    unsigned char* Ll = (unsigned char*)d_ws + 2129920;           //   532,480 B

    iou_kernel<<<BATCH * IOU_CB * GSPLIT, IOU_TPB, 0, stream>>>(
        boxes, gt_boxes, Hh, Ll);
    select_kernel<<<BATCH, 1024, 0, stream>>>(
        boxes, gt_boxes, gt_labels, noise, Hh, Ll, out);
}